// Round 3
// baseline (759.933 us; speedup 1.0000x reference)
//
#include <hip/hip_runtime.h>

#define NB   64
#define NT   30
#define NBT  1920        // NB*NT
#define EE   128
#define KP   28224       // 4*84*84
#define LTK  89          // 3*NT-1
#define NS   5696        // NB*LTK
#define NLY  6
#define NV   18
#define NZ   21          // split-K slabs for patch gemm

typedef unsigned short ushort_t;
using bf16x8 = __attribute__((ext_vector_type(8))) short;
using us8    = __attribute__((ext_vector_type(8))) unsigned short;
using f32x4  = __attribute__((ext_vector_type(4))) float;
using f32x16 = __attribute__((ext_vector_type(16))) float;

__device__ inline ushort_t f2bf(float f){
  union { float f; unsigned u; } v; v.f = f;
  unsigned r = v.u + 0x7FFFu + ((v.u >> 16) & 1u);   // RNE
  return (ushort_t)(r >> 16);
}
__device__ inline float bf2f(ushort_t h){
  union { unsigned u; float f; } v; v.u = ((unsigned)h) << 16; return v.f;
}

// ------- weights fp32->bf16 + inner transposes + qkv bias pack (1 launch) --
__global__ __launch_bounds__(256) void wcvt(
  const float* conv, const float* Wq, const float* Wk, const float* Wv,
  const float* Wo, const float* W1, const float* W2,
  const float* in_w, const float* out_w, const float* f1w, const float* f2w,
  const float* bq, const float* bk, const float* bv,
  ushort_t* dc, ushort_t* dqkv, ushort_t* dout, ushort_t* d1, ushort_t* d2,
  float* t_in, float* t_out, float* t_f1, float* t_f2, float* bqkv)
{
  if (blockIdx.x >= 4680){                  // transpose/pack tail
    int idx = (blockIdx.x-4680)*256 + threadIdx.x;
    if (idx < 384*128){ int j=idx>>7, k=idx&127; t_in[k*384+j]=in_w[idx]; }
    if (idx < 128*128){ int j=idx>>7, k=idx&127;
      t_out[k*128+j]=out_w[idx]; t_f1[k*128+j]=f1w[idx]; t_f2[k*128+j]=f2w[idx]; }
    if (idx < NLY*128){ int l=idx>>7, j=idx&127;
      bqkv[l*384+j]=bq[idx]; bqkv[l*384+128+j]=bk[idx]; bqkv[l*384+256+j]=bv[idx]; }
    return;
  }
  long i = 4l*((long)blockIdx.x*256 + threadIdx.x);
  if (i < 3612672l){
    float4 f = *reinterpret_cast<const float4*>(conv+i);
    dc[i]=f2bf(f.x); dc[i+1]=f2bf(f.y); dc[i+2]=f2bf(f.z); dc[i+3]=f2bf(f.w);
    return;
  }
  if (i < 3907584l){                       // Wq | Wk | Wv  ->  (L,384,128)
    long o = i - 3612672l;
    int  seg = (int)(o / 98304l);
    long off = o - (long)seg*98304l;
    long layer = off >> 14, rem = off & 16383l;
    const float* s = (seg==0) ? Wq : (seg==1) ? Wk : Wv;
    float4 f = *reinterpret_cast<const float4*>(s+off);
    long dst = layer*49152l + (long)seg*16384l + rem;
    dqkv[dst]=f2bf(f.x); dqkv[dst+1]=f2bf(f.y); dqkv[dst+2]=f2bf(f.z); dqkv[dst+3]=f2bf(f.w);
    return;
  }
  const float* s; ushort_t* d; long off;
  if      (i < 4005888l){ s=Wo; d=dout; off=i-3907584l; }
  else if (i < 4399104l){ s=W1; d=d1;   off=i-4005888l; }
  else                  { s=W2; d=d2;   off=i-4399104l; }
  float4 f = *reinterpret_cast<const float4*>(s+off);
  d[off]=f2bf(f.x); d[off+1]=f2bf(f.y); d[off+2]=f2bf(f.z); d[off+3]=f2bf(f.w);
}

// ---------------- patch embed: split-K into NZ disjoint slabs --------------
__global__ __launch_bounds__(256) void patch_gemm(
  const float* __restrict__ A, const ushort_t* __restrict__ Wb, float* __restrict__ C)
{
  __shared__ __align__(16) ushort_t As[32*64];
  __shared__ __align__(16) ushort_t Ws[128*64];
  const int tid = threadIdx.x, lane = tid & 63, wid = tid >> 6;
  const int wr = wid & 1, wc = wid >> 1;
  const int m0 = blockIdx.x * 32;
  const int kbase = blockIdx.z * 1344;
  float* Cz = C + (size_t)blockIdx.z * NBT * EE;
  f32x4 acc[4];
  #pragma unroll
  for (int j=0;j<4;j++) acc[j] = (f32x4){0.f,0.f,0.f,0.f};

  for (int kt = 0; kt < 21; ++kt){
    int k0 = kbase + kt*64;
    { int r = tid >> 3, kq = (tid & 7) * 8;
      const float* src = A + (size_t)(m0+r)*KP + k0 + kq;
      float4 f0 = *reinterpret_cast<const float4*>(src);
      float4 f1 = *reinterpret_cast<const float4*>(src+4);
      us8 o;
      o[0]=f2bf(f0.x); o[1]=f2bf(f0.y); o[2]=f2bf(f0.z); o[3]=f2bf(f0.w);
      o[4]=f2bf(f1.x); o[5]=f2bf(f1.y); o[6]=f2bf(f1.z); o[7]=f2bf(f1.w);
      *reinterpret_cast<us8*>(&As[r*64 + (kq ^ ((r&7)<<3))]) = o;
    }
    #pragma unroll
    for (int i=0;i<4;i++){
      int rr = (tid>>3) + 32*i, kq = (tid & 7) * 8;
      us8 v = *reinterpret_cast<const us8*>(Wb + (size_t)rr*KP + k0 + kq);
      *reinterpret_cast<us8*>(&Ws[rr*64 + (kq ^ ((rr&7)<<3))]) = v;
    }
    __syncthreads();
    #pragma unroll
    for (int ks=0; ks<2; ++ks){
      int ar = wr*16 + (lane&15);
      int kb = ks*32 + (lane>>4)*8;
      bf16x8 a = *reinterpret_cast<const bf16x8*>(&As[ar*64 + (kb ^ ((ar&7)<<3))]);
      #pragma unroll
      for (int j=0;j<4;j++){
        int nn = wc*64 + j*16 + (lane&15);
        bf16x8 b = *reinterpret_cast<const bf16x8*>(&Ws[nn*64 + (kb ^ ((nn&7)<<3))]);
        acc[j] = __builtin_amdgcn_mfma_f32_16x16x32_bf16(a, b, acc[j], 0,0,0);
      }
    }
    __syncthreads();
  }
  #pragma unroll
  for (int j=0;j<4;j++)
    #pragma unroll
    for (int rr=0;rr<4;rr++){
      int row = m0 + wr*16 + (lane>>4)*4 + rr;
      int col = wc*64 + j*16 + (lane&15);
      Cz[row*EE + col] = acc[j][rr];
    }
}

// ---------------- block-of-128 reduction helper ----------------------------
__device__ inline float bsum128(float v, volatile float* red){
  v += __shfl_xor(v,1);  v += __shfl_xor(v,2);  v += __shfl_xor(v,4);
  v += __shfl_xor(v,8);  v += __shfl_xor(v,16); v += __shfl_xor(v,32);
  int tid = threadIdx.x;
  if ((tid & 63) == 0) red[tid>>6] = v;
  __syncthreads();
  float s = red[0] + red[1];
  __syncthreads();
  return s;
}

// ---------------- inner TIT (one block per bt, 128 threads) ----------------
__global__ __launch_bounds__(128) void inner_tit(
  const float* __restrict__ part, const float* __restrict__ ctok,
  const float* __restrict__ t_in, const float* __restrict__ in_b,
  const float* __restrict__ t_out, const float* __restrict__ out_b,
  const float* __restrict__ g1, const float* __restrict__ b1_,
  const float* __restrict__ g2, const float* __restrict__ b2_,
  const float* __restrict__ t_f1, const float* __restrict__ fb1,
  const float* __restrict__ t_f2, const float* __restrict__ fb2,
  float* __restrict__ semb)
{
  int bt = blockIdx.x, e = threadIdx.x;
  __shared__ float xs[2][128], hs[2][128], qs[2][128], ks2[2][128], vs[2][128];
  __shared__ float red[2];
  {
    float acc = 0;
    #pragma unroll
    for (int z=0; z<NZ; ++z) acc += part[(size_t)z*NBT*EE + bt*128 + e];
    xs[0][e] = ctok[e];
    xs[1][e] = acc;
  }
  __syncthreads();
  for (int t=0;t<2;t++){
    float xv = xs[t][e];
    float m = bsum128(xv, red)*(1.f/128.f);
    float d = xv - m;
    float var = bsum128(d*d, red)*(1.f/128.f);
    hs[t][e] = d*rsqrtf(var+1e-5f)*g1[e] + b1_[e];
  }
  __syncthreads();
  for (int t=0;t<2;t++){
    float aq=in_b[e], ak=in_b[128+e], av=in_b[256+e];
    for (int kk=0;kk<128;kk++){
      float h = hs[t][kk];
      aq += h*t_in[kk*384+e]; ak += h*t_in[kk*384+128+e]; av += h*t_in[kk*384+256+e];
    }
    qs[t][e]=aq; ks2[t][e]=ak; vs[t][e]=av;
  }
  __syncthreads();
  const float sc = 0.08838834764831845f;
  float s00 = bsum128(qs[0][e]*ks2[0][e], red)*sc;
  float s01 = bsum128(qs[0][e]*ks2[1][e], red)*sc;
  float s10 = bsum128(qs[1][e]*ks2[0][e], red)*sc;
  float s11 = bsum128(qs[1][e]*ks2[1][e], red)*sc;
  {
    float m0 = fmaxf(s00,s01), p0=expf(s00-m0), p1=expf(s01-m0), iv=1.f/(p0+p1);
    hs[0][e] = (p0*vs[0][e] + p1*vs[1][e])*iv;
    float m1 = fmaxf(s10,s11), r0=expf(s10-m1), r1=expf(s11-m1), iw=1.f/(r0+r1);
    hs[1][e] = (r0*vs[0][e] + r1*vs[1][e])*iw;
  }
  __syncthreads();
  for (int t=0;t<2;t++){
    float o = out_b[e];
    for (int kk=0;kk<128;kk++) o += hs[t][kk]*t_out[kk*128+e];
    xs[t][e] += o;
  }
  __syncthreads();
  for (int t=0;t<2;t++){
    float xv = xs[t][e];
    float m = bsum128(xv, red)*(1.f/128.f);
    float d = xv - m;
    float var = bsum128(d*d, red)*(1.f/128.f);
    qs[t][e] = d*rsqrtf(var+1e-5f)*g2[e] + b2_[e];
  }
  __syncthreads();
  for (int t=0;t<2;t++){
    float a = fb1[e];
    for (int kk=0;kk<128;kk++) a += qs[t][kk]*t_f1[kk*128+e];
    hs[t][e] = fmaxf(a, 0.f);
  }
  __syncthreads();
  for (int t=0;t<2;t++){
    float a = fb2[e];
    for (int kk=0;kk<128;kk++) a += hs[t][kk]*t_f2[kk*128+e];
    xs[t][e] += a;
  }
  semb[bt*128+e] = xs[0][e];
}

// ============ fused per-layer attention kernel: one block per b ============
// LN1 + QKV(MFMA) + 8-head causal attention (MFMA) -> y (bf16).
// BUILD=true additionally constructs x (token interleave + pos) and writes it.
template<bool BUILD>
__global__ __launch_bounds__(256) void attn_layer(
  const float* __restrict__ x, const ushort_t* __restrict__ Wqkv,
  const float* __restrict__ bqkv, const float* __restrict__ lng,
  const float* __restrict__ lnb, ushort_t* __restrict__ y,
  const float* __restrict__ semb, const float* __restrict__ rtgs,
  const int* __restrict__ actions, const int* __restrict__ tsteps,
  const float* __restrict__ ret_w, const float* __restrict__ ret_b,
  const float* __restrict__ act_tab, const float* __restrict__ pos_emb,
  const float* __restrict__ gpos, float* __restrict__ xout)
{
  __shared__ __align__(16) ushort_t qa[96*128];     // Q, swizzled [row][h*16+d]
  __shared__ __align__(16) ushort_t ka[96*128];     // K, swizzled
  __shared__ __align__(16) ushort_t vta[128*104];   // V^T: [(h*16+d)][u], pitch 104
  __shared__ __align__(16) ushort_t u0[29568];      // union: ab+wb | S+pb+inv
  ushort_t* ab = u0;                                 // [96][128] bf16 swizzled
  ushort_t* wb = u0 + 12288;                         // [128][128] bf16 swizzled
  float*    S  = (float*)u0;                         // [96][101] fp32
  ushort_t* pb = u0 + 19392;                         // [96][104] bf16
  float*    inv= (float*)(u0 + 29376);               // [96]

  const int b = blockIdx.x;
  const int tid = threadIdx.x, lane = tid & 63, wid = tid >> 6;

  // ---- phase 0: (build x) + LN1 -> ab ----
  if (tid < 192){
    int row = tid >> 1, half = tid & 1;
    float xv[64];
    if (row < 89){
      int sg = b*LTK + row;
      if constexpr (BUILD){
        int t = row/3, m = row - 3*t;
        int ts = tsteps[b];
        #pragma unroll 8
        for (int i=0;i<64;i++){
          int e = half*64 + i;
          float tok;
          if      (m == 0) tok = tanhf(rtgs[b*NT+t]*ret_w[e] + ret_b[e]);
          else if (m == 1) tok = semb[(b*NT+t)*128 + e];
          else             tok = tanhf(act_tab[actions[b*NT+t+1]*128 + e]);
          float v = tok + gpos[(size_t)ts*128 + e] + pos_emb[row*128 + e];
          xv[i] = v;
          xout[(size_t)sg*128 + e] = v;
        }
      } else {
        const float* src = x + (size_t)sg*128 + half*64;
        #pragma unroll
        for (int i=0;i<16;i++){
          float4 f = *reinterpret_cast<const float4*>(src + 4*i);
          xv[4*i]=f.x; xv[4*i+1]=f.y; xv[4*i+2]=f.z; xv[4*i+3]=f.w;
        }
      }
      float s = 0;
      #pragma unroll
      for (int i=0;i<64;i++) s += xv[i];
      s += __shfl_xor(s,1);
      float mean = s*(1.0f/128.0f);
      float vs = 0;
      #pragma unroll
      for (int i=0;i<64;i++){ float d = xv[i]-mean; vs += d*d; }
      vs += __shfl_xor(vs,1);
      float rstd = rsqrtf(vs*(1.0f/128.0f) + 1e-5f);
      int sw = (row&7)<<3;
      #pragma unroll
      for (int g=0; g<8; ++g){
        int k = half*64 + g*8;
        us8 o;
        #pragma unroll
        for (int j=0;j<8;j++) o[j] = f2bf((xv[g*8+j]-mean)*rstd*lng[k+j] + lnb[k+j]);
        *reinterpret_cast<us8*>(&ab[row*128 + (k ^ sw)]) = o;
      }
    } else {          // rows 89..95 zero
      int sw = (row&7)<<3;
      #pragma unroll
      for (int g=0; g<8; ++g){
        int k = half*64 + g*8;
        *reinterpret_cast<us8*>(&ab[row*128 + (k ^ sw)]) = (us8){0,0,0,0,0,0,0,0};
      }
    }
  }

  // ---- phase 1: QKV gemm (seg 0=Q,1=K,2=V) ----
  for (int seg=0; seg<3; ++seg){
    __syncthreads();
    { int rr = tid >> 1, half = tid & 1;
      const ushort_t* src = Wqkv + (size_t)(seg*128+rr)*128 + half*64;
      int sw = (rr&7)<<3;
      #pragma unroll
      for (int g=0; g<8; ++g){
        us8 v = *reinterpret_cast<const us8*>(src + g*8);
        *reinterpret_cast<us8*>(&wb[rr*128 + ((half*64+g*8) ^ sw)]) = v;
      }
    }
    __syncthreads();
    for (int idx = wid; idx < 48; idx += 4){
      int rt = idx >> 3, nt = idx & 7;
      f32x4 acc = (f32x4){0.f,0.f,0.f,0.f};
      int arow = rt*16 + (lane&15), nrow = nt*16 + (lane&15);
      int asw = (arow&7)<<3, nsw = (nrow&7)<<3;
      #pragma unroll
      for (int ks=0; ks<4; ++ks){
        int kb = ks*32 + (lane>>4)*8;
        bf16x8 a = *reinterpret_cast<const bf16x8*>(&ab[arow*128 + (kb ^ asw)]);
        bf16x8 bfr = *reinterpret_cast<const bf16x8*>(&wb[nrow*128 + (kb ^ nsw)]);
        acc = __builtin_amdgcn_mfma_f32_16x16x32_bf16(a, bfr, acc, 0,0,0);
      }
      float bia = bqkv[seg*128 + nt*16 + (lane&15)];
      #pragma unroll
      for (int rr=0; rr<4; ++rr){
        int rg = rt*16 + (lane>>4)*4 + rr;
        ushort_t hv = f2bf(acc[rr] + bia);
        if (seg == 0)      qa[rg*128 + ((nt*16+(lane&15)) ^ ((rg&7)<<3))] = hv;
        else if (seg == 1) ka[rg*128 + ((nt*16+(lane&15)) ^ ((rg&7)<<3))] = hv;
        else               vta[(nt*16+(lane&15))*104 + rg] = hv;
      }
    }
  }
  __syncthreads();

  // ---- phase 2: per-head attention ----
  static const int TR[6] = {0,1,1,2,2,2};
  static const int TC[6] = {0,0,1,0,1,2};
  for (int h=0; h<8; ++h){
    // (a) S = Q K^T * 0.25  (32x32x16 MFMA, lower-triangle tiles)
    for (int idx = wid; idx < 6; idx += 4){
      int R = TR[idx], C = TC[idx];
      int arow = R*32 + (lane&31), brow = C*32 + (lane&31);
      int ke = h*16 + (lane>>5)*8;
      bf16x8 a = *reinterpret_cast<const bf16x8*>(&qa[arow*128 + (ke ^ ((arow&7)<<3))]);
      bf16x8 bfr = *reinterpret_cast<const bf16x8*>(&ka[brow*128 + (ke ^ ((brow&7)<<3))]);
      f32x16 sc = {};
      sc = __builtin_amdgcn_mfma_f32_32x32x16_bf16(a, bfr, sc, 0,0,0);
      #pragma unroll
      for (int r=0; r<16; ++r){
        int rin = (r&3) + 8*(r>>2) + 4*(lane>>5);
        S[(R*32+rin)*101 + C*32 + (lane&31)] = sc[r]*0.25f;
      }
    }
    __syncthreads();
    // (b) softmax rows -> pb (bf16), inv
    if (tid < 192){
      int t = tid >> 1, half = tid & 1;
      int u0i = half*48;
      float mx = -1e30f;
      if (t < 89){
        for (int u=u0i; u<u0i+48; ++u) if (u<=t) mx = fmaxf(mx, S[t*101+u]);
      }
      mx = fmaxf(mx, __shfl_xor(mx,1));
      float sm = 0;
      if (t < 89){
        for (int u=u0i; u<u0i+48; ++u){
          float p = 0;
          if (u<=t){ p = __expf(S[t*101+u]-mx); sm += p; }
          pb[t*104+u] = f2bf(p);
        }
      } else {
        for (int u=u0i; u<u0i+48; ++u) pb[t*104+u] = 0;
      }
      sm += __shfl_xor(sm,1);
      if (half==0) inv[t] = (t<89) ? 1.0f/sm : 0.0f;
    }
    __syncthreads();
    // (c) O = P V  (16x16x32 MFMA), write y
    for (int rt = wid; rt < 6; rt += 4){
      int arow = rt*16 + (lane&15);
      f32x4 acc = (f32x4){0.f,0.f,0.f,0.f};
      #pragma unroll
      for (int ks=0; ks<3; ++ks){
        int kb = ks*32 + (lane>>4)*8;
        bf16x8 a = *reinterpret_cast<const bf16x8*>(&pb[arow*104 + kb]);
        bf16x8 bfr = *reinterpret_cast<const bf16x8*>(&vta[(h*16+(lane&15))*104 + kb]);
        acc = __builtin_amdgcn_mfma_f32_16x16x32_bf16(a, bfr, acc, 0,0,0);
      }
      #pragma unroll
      for (int rr=0; rr<4; ++rr){
        int rg = rt*16 + (lane>>4)*4 + rr;
        if (rg < 89)
          y[(size_t)(b*LTK+rg)*128 + h*16 + (lane&15)] = f2bf(acc[rr]*inv[rg]);
      }
    }
    __syncthreads();
  }
}

// ============ fused per-layer FFN kernel: Wo+res+LN2+FFN+res ==============
// 89 blocks x 64 rows. x updated in place.
__global__ __launch_bounds__(256) void ffn_layer(
  const ushort_t* __restrict__ yg, const ushort_t* __restrict__ Wo,
  const float* __restrict__ bo, const float* __restrict__ g2,
  const float* __restrict__ b2g, const ushort_t* __restrict__ W1,
  const float* __restrict__ b1v, const ushort_t* __restrict__ W2,
  const float* __restrict__ b2v, float* __restrict__ x)
{
  __shared__ __align__(16) ushort_t f1s[64*512];   // FFN1 out; first 16KB = y tile
  __shared__ __align__(16) ushort_t wb[128*128];
  __shared__ float xres[64*132];
  __shared__ __align__(16) ushort_t h2[64*128];
  const int tid = threadIdx.x, lane = tid & 63, wid = tid >> 6;
  const int m0 = blockIdx.x * 64;

  // ---- phase A: o = y@Wo^T + bo + x ; LN2 -> h2 ----
  { int rr = tid >> 2, q = tid & 3;
    const ushort_t* src = yg + (size_t)(m0+rr)*128 + q*32;
    int sw = (rr&7)<<3;
    #pragma unroll
    for (int g=0; g<4; ++g){
      us8 v = *reinterpret_cast<const us8*>(src + g*8);
      *reinterpret_cast<us8*>(&f1s[rr*128 + ((q*32+g*8) ^ sw)]) = v;
    }
  }
  { int rr = tid >> 1, half = tid & 1;
    const ushort_t* src = Wo + (size_t)rr*128 + half*64;
    int sw = (rr&7)<<3;
    #pragma unroll
    for (int g=0; g<8; ++g){
      us8 v = *reinterpret_cast<const us8*>(src + g*8);
      *reinterpret_cast<us8*>(&wb[rr*128 + ((half*64+g*8) ^ sw)]) = v;
    }
  }
  __syncthreads();
  { int rt = wid;
    int arow = rt*16 + (lane&15);
    int asw = (arow&7)<<3;
    #pragma unroll
    for (int nt=0; nt<8; ++nt){
      f32x4 acc = (f32x4){0.f,0.f,0.f,0.f};
      int nrow = nt*16 + (lane&15), nsw = (nrow&7)<<3;
      #pragma unroll
      for (int ks=0; ks<4; ++ks){
        int kb = ks*32 + (lane>>4)*8;
        bf16x8 a = *reinterpret_cast<const bf16x8*>(&f1s[arow*128 + (kb ^ asw)]);
        bf16x8 bfr = *reinterpret_cast<const bf16x8*>(&wb[nrow*128 + (kb ^ nsw)]);
        acc = __builtin_amdgcn_mfma_f32_16x16x32_bf16(a, bfr, acc, 0,0,0);
      }
      int col = nt*16 + (lane&15);
      float bia = bo[col];
      #pragma unroll
      for (int rr=0; rr<4; ++rr){
        int row = rt*16 + (lane>>4)*4 + rr;
        float v = acc[rr] + bia + x[(size_t)(m0+row)*128 + col];
        xres[row*132 + col] = v;
      }
    }
  }
  __syncthreads();
  if (tid < 128){
    int row = tid >> 1, half = tid & 1;
    float xv[64];
    #pragma unroll
    for (int i=0;i<64;i++) xv[i] = xres[row*132 + half*64 + i];
    float s = 0;
    #pragma unroll
    for (int i=0;i<64;i++) s += xv[i];
    s += __shfl_xor(s,1);
    float mean = s*(1.0f/128.0f);
    float vs = 0;
    #pragma unroll
    for (int i=0;i<64;i++){ float d = xv[i]-mean; vs += d*d; }
    vs += __shfl_xor(vs,1);
    float rstd = rsqrtf(vs*(1.0f/128.0f) + 1e-5f);
    int sw = (row&7)<<3;
    #pragma unroll
    for (int g=0; g<8; ++g){
      int k = half*64 + g*8;
      us8 o;
      #pragma unroll
      for (int j=0;j<8;j++) o[j] = f2bf((xv[g*8+j]-mean)*rstd*g2[k+j] + b2g[k+j]);
      *reinterpret_cast<us8*>(&h2[row*128 + (k ^ sw)]) = o;
    }
  }

  // ---- phase B: f1 = gelu(h2@W1^T + b1), chunks of 128 cols ----
  for (int c=0; c<4; ++c){
    __syncthreads();
    { int rr = tid >> 1, half = tid & 1;
      const ushort_t* src = W1 + (size_t)(c*128+rr)*128 + half*64;
      int sw = (rr&7)<<3;
      #pragma unroll
      for (int g=0; g<8; ++g){
        us8 v = *reinterpret_cast<const us8*>(src + g*8);
        *reinterpret_cast<us8*>(&wb[rr*128 + ((half*64+g*8) ^ sw)]) = v;
      }
    }
    __syncthreads();
    int rt = wid;
    int arow = rt*16 + (lane&15);
    int asw = (arow&7)<<3;
    #pragma unroll
    for (int nt=0; nt<8; ++nt){
      f32x4 acc = (f32x4){0.f,0.f,0.f,0.f};
      int nrow = nt*16 + (lane&15), nsw = (nrow&7)<<3;
      #pragma unroll
      for (int ks=0; ks<4; ++ks){
        int kb = ks*32 + (lane>>4)*8;
        bf16x8 a = *reinterpret_cast<const bf16x8*>(&h2[arow*128 + (kb ^ asw)]);
        bf16x8 bfr = *reinterpret_cast<const bf16x8*>(&wb[nrow*128 + (kb ^ nsw)]);
        acc = __builtin_amdgcn_mfma_f32_16x16x32_bf16(a, bfr, acc, 0,0,0);
      }
      int colg = c*128 + nt*16 + (lane&15);
      float bia = b1v[colg];
      #pragma unroll
      for (int rr=0; rr<4; ++rr){
        int row = rt*16 + (lane>>4)*4 + rr;
        float v = acc[rr] + bia;
        v = 0.5f*v*(1.0f + erff(v*0.70710678118654752f));
        f1s[row*512 + (colg ^ ((row&7)<<3))] = f2bf(v);
      }
    }
  }

  // ---- phase C: x += f1@W2^T + b2 ----
  f32x4 acc2[8];
  #pragma unroll
  for (int nt=0; nt<8; ++nt) acc2[nt] = (f32x4){0.f,0.f,0.f,0.f};
  for (int c=0; c<4; ++c){
    __syncthreads();
    { int rr = tid >> 1, half = tid & 1;
      const ushort_t* src = W2 + (size_t)rr*512 + c*128 + half*64;
      int sw = (rr&7)<<3;
      #pragma unroll
      for (int g=0; g<8; ++g){
        us8 v = *reinterpret_cast<const us8*>(src + g*8);
        *reinterpret_cast<us8*>(&wb[rr*128 + ((half*64+g*8) ^ sw)]) = v;
      }
    }
    __syncthreads();
    int rt = wid;
    int arow = rt*16 + (lane&15);
    int asw = (arow&7)<<3;
    #pragma unroll
    for (int nt=0; nt<8; ++nt){
      int nrow = nt*16 + (lane&15), nsw = (nrow&7)<<3;
      #pragma unroll
      for (int ks=0; ks<4; ++ks){
        int kb = ks*32 + (lane>>4)*8;
        bf16x8 a = *reinterpret_cast<const bf16x8*>(&f1s[arow*512 + ((c*128+kb) ^ asw)]);
        bf16x8 bfr = *reinterpret_cast<const bf16x8*>(&wb[nrow*128 + (kb ^ nsw)]);
        acc2[nt] = __builtin_amdgcn_mfma_f32_16x16x32_bf16(a, bfr, acc2[nt], 0,0,0);
      }
    }
  }
  { int rt = wid;
    #pragma unroll
    for (int nt=0; nt<8; ++nt){
      int col = nt*16 + (lane&15);
      float bia = b2v[col];
      #pragma unroll
      for (int rr=0; rr<4; ++rr){
        int row = rt*16 + (lane>>4)*4 + rr;
        x[(size_t)(m0+row)*128 + col] = acc2[nt][rr] + bia + xres[row*132 + col];
      }
    }
  }
}

// ---------------- final LN + head on the 1920 state tokens -----------------
__global__ __launch_bounds__(128) void head_k(
  const float* __restrict__ x, const float* __restrict__ g,
  const float* __restrict__ bb, const float* __restrict__ hw,
  float* __restrict__ out)
{
  __shared__ float red[2];
  __shared__ float hsm[128];
  int bt = blockIdx.x;
  int b = bt/NT, t = bt - b*NT;
  int e = threadIdx.x;
  const float* row = x + (size_t)(b*LTK + 3*t + 1)*128;
  float xv = row[e];
  float m = bsum128(xv, red)*(1.f/128.f);
  float d = xv - m;
  float var = bsum128(d*d, red)*(1.f/128.f);
  hsm[e] = d*rsqrtf(var+1e-5f)*g[e] + bb[e];
  __syncthreads();
  int wv = e >> 6, ln = e & 63;
  for (int o = wv*9; o < wv*9+9; ++o){
    float s = hsm[ln]*hw[o*128+ln] + hsm[ln+64]*hw[o*128+ln+64];
    s += __shfl_xor(s,1); s += __shfl_xor(s,2); s += __shfl_xor(s,4);
    s += __shfl_xor(s,8); s += __shfl_xor(s,16); s += __shfl_xor(s,32);
    if (ln == 0) out[(size_t)(b*NT+t)*NV + o] = s;
  }
}

// ===========================================================================
extern "C" void kernel_launch(void* const* d_in, const int* in_sizes, int n_in,
                              void* d_out, int out_size, void* d_ws, size_t ws_size,
                              hipStream_t stream)
{
  const float* states  = (const float*)d_in[0];
  const int*   actions = (const int*)  d_in[1];
  const float* rtgs    = (const float*)d_in[2];
  const int*   tsteps  = (const int*)  d_in[3];
  const float* conv_w  = (const float*)d_in[4];
  const float* ctok    = (const float*)d_in[5];
  const float* in_w    = (const float*)d_in[6];
  const float* in_b    = (const float*)d_in[7];
  const float* out_w   = (const float*)d_in[8];
  const float* out_b   = (const float*)d_in[9];
  const float* i1g     = (const float*)d_in[10];
  const float* i1b     = (const float*)d_in[11];
  const float* i2g     = (const float*)d_in[12];
  const float* i2b     = (const float*)d_in[13];
  const float* fw1     = (const float*)d_in[14];
  const float* fb1     = (const float*)d_in[15];
  const float* fw2     = (const float*)d_in[16];
  const float* fb2     = (const float*)d_in[17];
  const float* ret_w   = (const float*)d_in[18];
  const float* ret_b   = (const float*)d_in[19];
  const float* act_tab = (const float*)d_in[20];
  const float* pos_emb = (const float*)d_in[21];
  const float* gpos    = (const float*)d_in[22];
  const float* ln1g    = (const float*)d_in[23];
  const float* ln1b    = (const float*)d_in[24];
  const float* Wq      = (const float*)d_in[25];
  const float* bq      = (const float*)d_in[26];
  const float* Wk      = (const float*)d_in[27];
  const float* bk      = (const float*)d_in[28];
  const float* Wv      = (const float*)d_in[29];
  const float* bv      = (const float*)d_in[30];
  const float* Wo      = (const float*)d_in[31];
  const float* bo      = (const float*)d_in[32];
  const float* ln2g    = (const float*)d_in[33];
  const float* ln2b    = (const float*)d_in[34];
  const float* W1      = (const float*)d_in[35];
  const float* b1      = (const float*)d_in[36];
  const float* W2      = (const float*)d_in[37];
  const float* b2      = (const float*)d_in[38];
  const float* lnfg    = (const float*)d_in[39];
  const float* lnfb    = (const float*)d_in[40];
  const float* head_w  = (const float*)d_in[41];

  char* w = (char*)d_ws;
  size_t off = 0;
  auto alloc = [&](size_t bytes)->char* {
    char* p = w + off; off += (bytes + 255) & ~(size_t)255; return p;
  };
  float*    part  = (float*)   alloc((size_t)NZ*NBT*EE*4);
  float*    semb  = (float*)   alloc((size_t)NBT*EE*4);
  float*    x     = (float*)   alloc((size_t)NS*EE*4);
  ushort_t* yb    = (ushort_t*)alloc((size_t)NS*EE*2);
  ushort_t* cwb   = (ushort_t*)alloc((size_t)EE*KP*2);
  ushort_t* Wqkvb = (ushort_t*)alloc((size_t)NLY*384*128*2);
  ushort_t* Wob   = (ushort_t*)alloc((size_t)NLY*128*128*2);
  ushort_t* W1b   = (ushort_t*)alloc((size_t)NLY*512*128*2);
  ushort_t* W2b   = (ushort_t*)alloc((size_t)NLY*128*512*2);
  float*    t_in  = (float*)   alloc(384*128*4);
  float*    t_out = (float*)   alloc(128*128*4);
  float*    t_f1  = (float*)   alloc(128*128*4);
  float*    t_f2  = (float*)   alloc(128*128*4);
  float*    bqkv  = (float*)   alloc(NLY*384*4);
  (void)in_sizes; (void)n_in; (void)out_size; (void)ws_size;

  wcvt<<<4872,256,0,stream>>>(conv_w,Wq,Wk,Wv,Wo,W1,W2,
                              in_w,out_w,fw1,fw2, bq,bk,bv,
                              cwb,Wqkvb,Wob,W1b,W2b,
                              t_in,t_out,t_f1,t_f2, bqkv);
  patch_gemm<<<dim3(60,1,NZ),256,0,stream>>>(states, cwb, part);
  inner_tit<<<NBT,128,0,stream>>>(part, ctok, t_in, in_b, t_out, out_b,
                                  i1g,i1b,i2g,i2b, t_f1,fb1, t_f2,fb2, semb);
  for (int i=0;i<NLY;i++){
    if (i == 0)
      attn_layer<true><<<NB,256,0,stream>>>(
        x, Wqkvb, bqkv, ln1g, ln1b, yb,
        semb, rtgs, actions, tsteps, ret_w, ret_b, act_tab, pos_emb, gpos, x);
    else
      attn_layer<false><<<NB,256,0,stream>>>(
        x, Wqkvb+(size_t)i*49152, bqkv+(size_t)i*384, ln1g+i*128, ln1b+i*128, yb,
        nullptr, nullptr, nullptr, nullptr, nullptr, nullptr, nullptr, nullptr,
        nullptr, nullptr);
    ffn_layer<<<89,256,0,stream>>>(
      yb, Wob+(size_t)i*16384, bo+i*128, ln2g+i*128, ln2b+i*128,
      W1b+(size_t)i*65536, b1+i*512, W2b+(size_t)i*65536, b2+i*128, x);
  }
  head_k<<<NBT,128,0,stream>>>(x, lnfg, lnfb, head_w, (float*)d_out);
}